// Round 4
// baseline (291.189 us; speedup 1.0000x reference)
//
#include <hip/hip_runtime.h>
#include <hip/hip_bf16.h>

typedef __attribute__((ext_vector_type(8))) short short8;
typedef __attribute__((ext_vector_type(4))) float f32x4;

__device__ __forceinline__ short8 load_af(const unsigned short* p) {
  union { uint2 u[2]; short8 v; } r;
  r.u[0] = *(const uint2*)(p);        // k = k0..k0+3
  r.u[1] = *(const uint2*)(p + 16);   // k = k0+16..k0+19
  return r.v;
}

__device__ __forceinline__ unsigned int pk_bf16(float a, float b) {
  __hip_bfloat162 h = __float22bfloat162_rn(make_float2(a, b));
  return *(unsigned int*)&h;
}
__device__ __forceinline__ unsigned short s_bf16(float a) {
  __hip_bfloat16 h = __float2bfloat16(a);
  return *(unsigned short*)&h;
}

// ---------------------------------------------------------------------------
// prep (fused): build all MFMA B-fragments directly.
//   fL1 tile (nt,kk): element (lane,e) = DW1[k(l,e)][nt*16+(l&15)],
//   DW1[n][j] = sum_m cos(2pi m n/1024) W1[2m][j] - sin(2pi m n/1024) W1[2m+1][j]
//   computed per-lane with an 8-phasor rotation recurrence (no tables, no dw1).
//   k(l,e) = kk*32 + 4*(l>>4) + (e&3) + 16*(e>>2)
// fL2/fL3: plain swizzle of W2/W3.
// wave w = tile id: 0..511 -> fL1, 512..575 -> fL2, 576..583 -> fL3.
// ---------------------------------------------------------------------------
__global__ __launch_bounds__(256) void prep_kernel(
    const float* __restrict__ W1, const float* __restrict__ W2,
    const float* __restrict__ W3,
    unsigned short* __restrict__ fL1, unsigned short* __restrict__ fL2,
    unsigned short* __restrict__ fL3) {
  const int w = blockIdx.x * 4 + (threadIdx.x >> 6);
  const int lane = threadIdx.x & 63;
  const int rlo = lane & 15;
  const int q4 = (lane >> 4) << 2;

  if (w < 512) {
    const int nt = w >> 5, kk = w & 31;
    const int col = nt * 16 + rlo;
    const int k0 = kk * 32 + q4;
    float pc[8], ps[8], dc[8], dsn[8], acc[8];
#pragma unroll
    for (int e = 0; e < 8; ++e) {
      int ke = k0 + (e & 3) + ((e >> 2) << 4);
      float ang = (float)ke * 6.135923151542565e-3f;  // 2*pi/1024
      float s, c;
      __sincosf(ang, &s, &c);
      dc[e] = c; dsn[e] = s;
      pc[e] = 1.f; ps[e] = 0.f;
      acc[e] = 0.f;
    }
    const float* pw = W1 + col;
#pragma unroll 2
    for (int m = 0; m < 192; ++m) {
      float wre = pw[0];     // W1[2m][col]
      float wio = pw[256];   // W1[2m+1][col]
      pw += 512;
#pragma unroll
      for (int e = 0; e < 8; ++e) {
        acc[e] = fmaf(pc[e], wre, acc[e]);
        acc[e] = fmaf(-ps[e], wio, acc[e]);
        float c2 = pc[e] * dc[e] - ps[e] * dsn[e];
        float s2 = ps[e] * dc[e] + pc[e] * dsn[e];
        pc[e] = c2; ps[e] = s2;
      }
    }
    uint4 v;
    v.x = pk_bf16(acc[0], acc[1]);
    v.y = pk_bf16(acc[2], acc[3]);
    v.z = pk_bf16(acc[4], acc[5]);
    v.w = pk_bf16(acc[6], acc[7]);
    *(uint4*)(fL1 + ((size_t)w * 64 + lane) * 8) = v;
  } else if (w < 576) {
    const int tl = w - 512;
    const int nt = tl >> 3, kk = tl & 7;
    const int col = nt * 16 + rlo;
    const int k0 = kk * 32 + q4;
    float a[8];
#pragma unroll
    for (int e = 0; e < 8; ++e) {
      int ke = k0 + (e & 3) + ((e >> 2) << 4);
      a[e] = W2[ke * 128 + col];
    }
    uint4 v;
    v.x = pk_bf16(a[0], a[1]); v.y = pk_bf16(a[2], a[3]);
    v.z = pk_bf16(a[4], a[5]); v.w = pk_bf16(a[6], a[7]);
    *(uint4*)(fL2 + ((size_t)tl * 64 + lane) * 8) = v;
  } else {
    const int tl = w - 576;
    const int nt = tl >> 2, kk = tl & 3;
    const int col = nt * 16 + rlo;
    const int k0 = kk * 32 + q4;
    float a[8];
#pragma unroll
    for (int e = 0; e < 8; ++e) {
      int ke = k0 + (e & 3) + ((e >> 2) << 4);
      a[e] = W3[ke * 32 + col];
    }
    uint4 v;
    v.x = pk_bf16(a[0], a[1]); v.y = pk_bf16(a[2], a[3]);
    v.z = pk_bf16(a[4], a[5]); v.w = pk_bf16(a[6], a[7]);
    *(uint4*)(fL3 + ((size_t)tl * 64 + lane) * 8) = v;
  }
}

// ---------------------------------------------------------------------------
// fused MLP. 512 blocks x 256 thr (4 waves), BM=64.
// LDS overlay: phase-1 x staging (double-buffered) reuses the same memory as
// the phase-2/3 h1/h2 buffers -> 49 KB -> 3 blocks/CU.
// Strides: row stride == 8 (mod 128) bytes -> b64 A-reads hit the 4-cycle
// bank minimum (balanced 4-over-even-banks pattern).
// ---------------------------------------------------------------------------
#define XS_S 132   // ushorts: 264 B
#define H1_S 260   // 520 B
#define H2_S 132

struct P2 {
  unsigned short h1[64 * H1_S];
  unsigned short h2[64 * H2_S];
};
union SH {
  unsigned short xs[2][64 * XS_S];
  P2 p2;
};

__global__ __launch_bounds__(256, 3) void mlp_kernel(
    const float* __restrict__ x,
    const float* __restrict__ b1, const float* __restrict__ b2,
    const float* __restrict__ b3,
    const unsigned short* __restrict__ fL1, const unsigned short* __restrict__ fL2,
    const unsigned short* __restrict__ fL3, float* __restrict__ out) {
  __shared__ SH sh;
  const int t = threadIdx.x;
  const int lane = t & 63;
  const int wid = t >> 6;
  const int rlo = lane & 15;
  const int g4 = (lane >> 4) << 2;
  const size_t row0 = (size_t)blockIdx.x * 64;
  const float* xb = x + row0 * 1024;

  f32x4 acc[4][4] = {};

  // prologue: load chunk 0 into regs
  float4 st[8];
#pragma unroll
  for (int i = 0; i < 8; ++i) {
    int idx = i * 256 + t;
    int row = idx >> 5, cg = idx & 31;
    st[i] = *(const float4*)(xb + row * 1024 + cg * 4);
  }

  for (int kc = 0; kc < 8; ++kc) {
    unsigned short* xbuf = sh.xs[kc & 1];
    // write current chunk regs -> LDS (packed bf16)
#pragma unroll
    for (int i = 0; i < 8; ++i) {
      int idx = i * 256 + t;
      int row = idx >> 5, cg = idx & 31;
      uint2 wv;
      wv.x = pk_bf16(st[i].x, st[i].y);
      wv.y = pk_bf16(st[i].z, st[i].w);
      *(uint2*)(xbuf + row * XS_S + cg * 4) = wv;
    }
    // issue next chunk's global loads -- they fly under barrier+MFMA
    if (kc < 7) {
#pragma unroll
      for (int i = 0; i < 8; ++i) {
        int idx = i * 256 + t;
        int row = idx >> 5, cg = idx & 31;
        st[i] = *(const float4*)(xb + row * 1024 + (kc + 1) * 128 + cg * 4);
      }
    }
    // prefetch first ks B-fragments before the barrier (independent of LDS)
    short8 bcur[4];
#pragma unroll
    for (int c = 0; c < 4; ++c)
      bcur[c] = *(const short8*)(fL1 +
                (((size_t)(wid * 4 + c) * 32 + kc * 4) * 64 + lane) * 8);
    __syncthreads();
#pragma unroll
    for (int ks = 0; ks < 4; ++ks) {
      short8 bnext[4];
      if (ks < 3) {
#pragma unroll
        for (int c = 0; c < 4; ++c)
          bnext[c] = *(const short8*)(fL1 +
                    (((size_t)(wid * 4 + c) * 32 + kc * 4 + ks + 1) * 64 + lane) * 8);
      }
      short8 af[4];
#pragma unroll
      for (int m = 0; m < 4; ++m)
        af[m] = load_af(xbuf + (m * 16 + rlo) * XS_S + ks * 32 + g4);
#pragma unroll
      for (int m = 0; m < 4; ++m)
#pragma unroll
        for (int c = 0; c < 4; ++c)
          acc[m][c] = __builtin_amdgcn_mfma_f32_16x16x32_bf16(af[m], bcur[c], acc[m][c], 0, 0, 0);
      if (ks < 3) {
#pragma unroll
        for (int c = 0; c < 4; ++c) bcur[c] = bnext[c];
      }
    }
    // next iteration's ds_write targets the other buffer; the single barrier
    // per iteration separates write(kc+1) from MFMA(kc) reads. The union's h1
    // area is only touched after the loop + barrier below.
  }
  __syncthreads();

  // ---- L1 epilogue: bias + leaky -> h1 (bf16)
  {
    float bv[4];
#pragma unroll
    for (int c = 0; c < 4; ++c) bv[c] = b1[wid * 64 + c * 16 + rlo];
#pragma unroll
    for (int m = 0; m < 4; ++m)
#pragma unroll
      for (int c = 0; c < 4; ++c)
#pragma unroll
        for (int r = 0; r < 4; ++r) {
          float v = acc[m][c][r] + bv[c];
          v = fmaxf(v, 0.01f * v);
          sh.p2.h1[(m * 16 + g4 + r) * H1_S + wid * 64 + c * 16 + rlo] = s_bf16(v);
        }
  }
  __syncthreads();

  // ---- L2: 64 rows x 32 cols per wave, K = 256
  f32x4 a2[4][2] = {};
#pragma unroll
  for (int ks = 0; ks < 8; ++ks) {
    short8 af[4];
#pragma unroll
    for (int m = 0; m < 4; ++m)
      af[m] = load_af(sh.p2.h1 + (m * 16 + rlo) * H1_S + ks * 32 + g4);
    short8 bfr[2];
#pragma unroll
    for (int c = 0; c < 2; ++c)
      bfr[c] = *(const short8*)(fL2 + (((size_t)(wid * 2 + c) * 8 + ks) * 64 + lane) * 8);
#pragma unroll
    for (int m = 0; m < 4; ++m)
#pragma unroll
      for (int c = 0; c < 2; ++c)
        a2[m][c] = __builtin_amdgcn_mfma_f32_16x16x32_bf16(af[m], bfr[c], a2[m][c], 0, 0, 0);
  }
  {
    float bv[2];
#pragma unroll
    for (int c = 0; c < 2; ++c) bv[c] = b2[wid * 32 + c * 16 + rlo];
#pragma unroll
    for (int m = 0; m < 4; ++m)
#pragma unroll
      for (int c = 0; c < 2; ++c)
#pragma unroll
        for (int r = 0; r < 4; ++r) {
          float v = a2[m][c][r] + bv[c];
          v = fmaxf(v, 0.01f * v);
          sh.p2.h2[(m * 16 + g4 + r) * H2_S + wid * 32 + c * 16 + rlo] = s_bf16(v);
        }
  }
  __syncthreads();

  // ---- L3: rowtile = wid (16 rows) x 32 cols, K = 128, no activation
  f32x4 a3[2] = {};
#pragma unroll
  for (int ks = 0; ks < 4; ++ks) {
    short8 af = load_af(sh.p2.h2 + (wid * 16 + rlo) * H2_S + ks * 32 + g4);
#pragma unroll
    for (int c = 0; c < 2; ++c) {
      short8 bfr = *(const short8*)(fL3 + (((size_t)c * 4 + ks) * 64 + lane) * 8);
      a3[c] = __builtin_amdgcn_mfma_f32_16x16x32_bf16(af, bfr, a3[c], 0, 0, 0);
    }
  }
  {
    float bv[2];
    bv[0] = b3[rlo];
    bv[1] = b3[16 + rlo];
#pragma unroll
    for (int c = 0; c < 2; ++c)
#pragma unroll
      for (int r = 0; r < 4; ++r)
        out[(row0 + wid * 16 + g4 + r) * 32 + c * 16 + rlo] = a3[c][r] + bv[c];
  }
}

// ---------------------------------------------------------------------------
extern "C" void kernel_launch(void* const* d_in, const int* in_sizes, int n_in,
                              void* d_out, int out_size, void* d_ws, size_t ws_size,
                              hipStream_t stream) {
  const float* x  = (const float*)d_in[0];
  const float* W1 = (const float*)d_in[1];
  const float* b1 = (const float*)d_in[2];
  const float* W2 = (const float*)d_in[3];
  const float* b2 = (const float*)d_in[4];
  const float* W3 = (const float*)d_in[5];
  const float* b3 = (const float*)d_in[6];
  float* out = (float*)d_out;

  char* ws = (char*)d_ws;
  unsigned short* fL1 = (unsigned short*)ws;                 // 512 KiB
  unsigned short* fL2 = (unsigned short*)(ws + 524288);      //  64 KiB
  unsigned short* fL3 = (unsigned short*)(ws + 589824);      //   8 KiB

  hipLaunchKernelGGL(prep_kernel, dim3(146), dim3(256), 0, stream,
                     W1, W2, W3, fL1, fL2, fL3);
  hipLaunchKernelGGL(mlp_kernel, dim3(512), dim3(256), 0, stream,
                     x, b1, b2, b3, fL1, fL2, fL3, out);
}